// Round 5
// baseline (846.099 us; speedup 1.0000x reference)
//
#include <hip/hip_runtime.h>
#include <cmath>

// Problem constants
#define Bsz 32
#define Lsz 256
#define Asz 20
#define NCHUNK 8        // p-chunks per i (32 p each)
#define PCH 32          // L / NCHUNK
#define GRP 16          // blocks staged per LDS group (16*400 = 6400 floats)
#define NGRP 2          // groups per chunk
#define BLK1 640        // t = j*32 + b  (j=t>>5 in 0..19, b=t&31)

// Workspace offsets (floats). Total ~1.43M floats = 5.7 MB.
#define OFF_G 0                                    // [c][i][b][j] p>i gather partials
#define OFF_C (NCHUNK*Lsz*Bsz*Asz)                 // [c][i][j]    b-independent (p<=i)
#define OFF_E (OFF_C + NCHUNK*Lsz*Asz)             // [c][i][b]    energy pair partials
#define OFF_RSQ (OFF_E + NCHUNK*Lsz*Bsz)           // [2048] per-wg sum w^2
#define OFF_RAB (OFF_RSQ + NCHUNK*Lsz)             // [2048] per-wg sum |w|
#define OFF_K2  (OFF_RAB + NCHUNK*Lsz)             // [L*B]  per-(i,b) lse-energy
#define OFF_TICKI (OFF_K2 + Lsz*Bsz)               // [256] per-i arrival counters (int)
#define OFF_TICKG (OFF_TICKI + Lsz)                // [1]   global arrival counter (int)

// Single fused kernel: wg = (i, chunk c), grid 2048.
// Hot path identical to the proven round-0 k1. The LAST of the 8 wgs for a
// given i (per-i device-scope ticket) assembles that i's logits + lse (former
// k2); the LAST of those 256 finishers (global ticket) does the final scalar
// reduction (former k3). Tickets are zeroed by a 1 KB hipMemsetAsync.
__global__ __launch_bounds__(BLK1, 8) void k1(const int* __restrict__ x,
                                              const float* __restrict__ wsng,
                                              const float* __restrict__ wp,
                                              float* __restrict__ ws,
                                              float* __restrict__ out) {
  const int wg = blockIdx.x;
  const int c = wg & (NCHUNK - 1);
  const int i = wg >> 3;
  const int t = threadIdx.x;
  const int j = t >> 5;         // 0..19
  const int b = t & 31;         // 0..31

  __shared__ float blk[GRP * 400];   // 25.6 KB (reused as logit table in finisher)
  __shared__ int   xs[PCH * Bsz];    // [dp][b] -> bank = b, conflict-free
  __shared__ int   xi[Bsz];
  __shared__ float wred[32];
  __shared__ int   lastFlag, glastFlag;

  const int pbase = c * PCH;
  for (int k = t; k < PCH * Bsz; k += BLK1) {
    int dp = k >> 5, bb = k & 31;
    xs[k] = x[bb * Lsz + pbase + dp];
  }
  if (t < Bsz) xi[t] = x[t * Lsz + i];

  float accJ = 0.f, accE = 0.f, accC = 0.f, rsq = 0.f, rab = 0.f;

  // chunk = 12800 floats = 3200 float4; group = 1600 float4
  const float4* wrow = (const float4*)(wp + (size_t)(i * Lsz + pbase) * 400);
  float4 v0 = wrow[t];
  float4 v1 = wrow[t + 640];
  float4 v2 = (t < 320) ? wrow[t + 1280] : make_float4(0.f, 0.f, 0.f, 0.f);

  for (int g = 0; g < NGRP; ++g) {
    // stage current group: contiguous b128 writes, no index math
    float4* bf4 = (float4*)blk;
    bf4[t] = v0;
    bf4[t + 640] = v1;
    if (t < 320) bf4[t + 1280] = v2;
    rsq += v0.x*v0.x + v0.y*v0.y + v0.z*v0.z + v0.w*v0.w;
    rsq += v1.x*v1.x + v1.y*v1.y + v1.z*v1.z + v1.w*v1.w;
    rab += fabsf(v0.x)+fabsf(v0.y)+fabsf(v0.z)+fabsf(v0.w);
    rab += fabsf(v1.x)+fabsf(v1.y)+fabsf(v1.z)+fabsf(v1.w);
    if (t < 320) {
      rsq += v2.x*v2.x + v2.y*v2.y + v2.z*v2.z + v2.w*v2.w;
      rab += fabsf(v2.x)+fabsf(v2.y)+fabsf(v2.z)+fabsf(v2.w);
    }
    __syncthreads();

    // prefetch next group (register path overlaps barrier+gather)
    if (g == 0) {
      v0 = wrow[1600 + t];
      v1 = wrow[1600 + t + 640];
      if (t < 320) v2 = wrow[1600 + t + 1280];
    }

    const int p0 = pbase + g * GRP;   // global p of LDS block 0
    // --- accJ: p > i, all waves, uniform trip count ---
    int ppstart = i + 1 - p0;
    if (ppstart < 0) ppstart = 0;
    const int jbase = j * Asz;
    for (int pp = ppstart; pp < GRP; ++pp) {
      int xv = xs[((g * GRP + pp) << 5) | b];
      accJ += blk[pp * 400 + jbase + xv];
    }
    // --- accE (lanes 0..31 of wave 0): all p ---
    if (t < Bsz) {
      const int ebase = xi[t] * Asz;
      for (int pp = 0; pp < GRP; ++pp) {
        int xv = xs[((g * GRP + pp) << 5) | t];
        accE += blk[pp * 400 + ebase + xv];
      }
    } else if (t < Bsz + Asz) {
      // --- accC (lanes 32..51 of wave 0): p<i -> col 19; p==i -> diag ---
      const int jj = t - Bsz;
      int pend = i - p0;
      if (pend > GRP) pend = GRP;
      for (int pp = 0; pp < pend; ++pp) accC += blk[pp * 400 + jj * Asz + 19];
      const int pd = i - p0;
      if (pd >= 0 && pd < GRP) accC += blk[pd * 400 + jj * Asz + jj];
    }
    __syncthreads();
  }

  ws[OFF_G + ((size_t)(c * Lsz + i) * Bsz + b) * Asz + j] = accJ;
  if (t < Bsz) ws[OFF_E + (c * Lsz + i) * Bsz + t] = accE;
  else if (t < Bsz + Asz) ws[OFF_C + (c * Lsz + i) * Asz + (t - Bsz)] = accC;

  // reg-stat reduction: wave shuffle then tiny LDS pass
  for (int s = 32; s >= 1; s >>= 1) {
    rsq += __shfl_down(rsq, s);
    rab += __shfl_down(rab, s);
  }
  if ((t & 63) == 0) { wred[t >> 6] = rsq; wred[16 + (t >> 6)] = rab; }
  __syncthreads();
  if (t == 0) {
    float a = 0.f, bb = 0.f;
    for (int w = 0; w < 10; ++w) { a += wred[w]; bb += wred[16 + w]; }
    ws[OFF_RSQ + wg] = a;
    ws[OFF_RAB + wg] = bb;
  }

  // ---- per-i arrival ticket: last of the 8 chunk-wgs finishes row i ----
  __syncthreads();   // all threads' partial stores are program-complete
  if (t == 0) {
    __threadfence(); // release this wg's partials (device scope)
    int old = __hip_atomic_fetch_add((int*)(ws + OFF_TICKI) + i, 1,
                                     __ATOMIC_ACQ_REL, __HIP_MEMORY_SCOPE_AGENT);
    lastFlag = (old == NCHUNK - 1);
  }
  __syncthreads();
  if (!lastFlag) return;
  __threadfence();   // acquire: all 8 chunk-partials for this i visible

  // ---- former k2 body for row i (reuses blk as the 32x21 logit table) ----
  {
    float v = wsng[i * Asz + j];
    #pragma unroll
    for (int cc = 0; cc < NCHUNK; ++cc) {
      v += ws[OFF_C + (cc * Lsz + i) * Asz + j];
      v += ws[OFF_G + ((size_t)(cc * Lsz + i) * Bsz + b) * Asz + j];
    }
    blk[b * 21 + j] = v;
  }
  __syncthreads();

  if (t < Bsz) {
    float m = -1e30f;
    #pragma unroll
    for (int jj = 0; jj < Asz; ++jj) m = fmaxf(m, blk[t * 21 + jj]);
    float se = 0.f;
    #pragma unroll
    for (int jj = 0; jj < Asz; ++jj) se += __expf(blk[t * 21 + jj] - m);
    float lse = m + __logf(se);
    float en = wsng[i * Asz + xi[t]];
    #pragma unroll
    for (int cc = 0; cc < NCHUNK; ++cc) en += ws[OFF_E + (cc * Lsz + i) * Bsz + t];
    ws[OFF_K2 + i * Bsz + t] = lse - en;
  }

  // ---- global arrival ticket: last finisher does the final reduction ----
  __syncthreads();
  if (t == 0) {
    __threadfence();
    int old = __hip_atomic_fetch_add((int*)(ws + OFF_TICKG), 1,
                                     __ATOMIC_ACQ_REL, __HIP_MEMORY_SCOPE_AGENT);
    glastFlag = (old == Lsz - 1);
  }
  __syncthreads();
  if (!glastFlag) return;
  __threadfence();

  // ---- former k3 body, strided over 640 threads ----
  float ssq = 0.f, sab = 0.f;
  for (int k = t; k < Lsz * Asz; k += BLK1) {
    float w = wsng[k];
    ssq += w * w; sab += fabsf(w);
  }
  float psq = 0.f, pab = 0.f;
  for (int k = t; k < NCHUNK * Lsz; k += BLK1) {
    psq += ws[OFF_RSQ + k];
    pab += ws[OFF_RAB + k];
  }
  float fe = 0.f;
  for (int k = t; k < Lsz * Bsz; k += BLK1) fe += ws[OFF_K2 + k];

  const float LP = 51.0f;  // 0.2 * (L-1)
  float val = fe * (1.0f / Bsz) + (ssq + sab) + LP * (psq + pab);

  for (int s = 32; s >= 1; s >>= 1) val += __shfl_down(val, s);
  if ((t & 63) == 0) wred[t >> 6] = val;
  __syncthreads();
  if (t == 0) {
    float a = 0.f;
    for (int w = 0; w < BLK1 / 64; ++w) a += wred[w];
    out[0] = a;
  }
}

extern "C" void kernel_launch(void* const* d_in, const int* in_sizes, int n_in,
                              void* d_out, int out_size, void* d_ws, size_t ws_size,
                              hipStream_t stream) {
  const int*   x       = (const int*)d_in[0];
  const float* wsingle = (const float*)d_in[1];
  const float* wpair   = (const float*)d_in[2];
  float* ws  = (float*)d_ws;
  float* out = (float*)d_out;

  // zero the 257 arrival tickets (1 KB; stream op, graph-capture-safe)
  hipMemsetAsync((void*)(ws + OFF_TICKI), 0, (Lsz + 1) * sizeof(int), stream);
  k1<<<Lsz * NCHUNK, BLK1, 0, stream>>>(x, wsingle, wpair, ws, out);
}

// Round 6
// 179.121 us; speedup vs baseline: 4.7236x; 4.7236x over previous
//
#include <hip/hip_runtime.h>
#include <cmath>

// Problem constants
#define Bsz 32
#define Lsz 256
#define Asz 20
#define NCHUNK 8        // p-chunks per i (32 p each)
#define PCH 32          // L / NCHUNK
#define GRP 16          // blocks staged per LDS group (16*400 = 6400 floats)
#define NGRP 2          // groups per chunk
#define BLK1 512        // 8 waves: row r = t>>5 (0..15) owns j=r; rows 0..3 also j=16+r
#define BLK2 640        // k2: t = j*32 + b

// Workspace offsets (floats). Total ~1.43M floats = 5.7 MB.
#define OFF_G 0                                    // [c][i][b][j] p>i gather partials
#define OFF_C (NCHUNK*Lsz*Bsz*Asz)                 // [c][i][j]    b-independent (p<=i)
#define OFF_E (OFF_C + NCHUNK*Lsz*Asz)             // [c][i][b]    energy pair partials
#define OFF_RSQ (OFF_E + NCHUNK*Lsz*Bsz)           // [2048] per-wg sum w^2
#define OFF_RAB (OFF_RSQ + NCHUNK*Lsz)             // [2048] per-wg sum |w|
#define OFF_K2  (OFF_RAB + NCHUNK*Lsz)             // [L*B]  per-(i,b) lse-energy
#define OFF_TICKET (OFF_K2 + Lsz*Bsz)              // [1]    k2 arrival counter (int)

// Kernel 1: stream all of w_pair once. wg = (i, chunk c), grid 2048.
// 512-thread blocks -> 4 wgs/CU (32 waves) -> grid = EXACTLY 2 wavesets
// (640-thread version had 2.67 wavesets = 11% ragged-tail idle).
// Register-staged (no global_load_lds, no device fences on the hot path).
__global__ __launch_bounds__(BLK1, 8) void k1(const int* __restrict__ x,
                                              const float* __restrict__ wp,
                                              float* __restrict__ ws) {
  const int wg = blockIdx.x;
  const int c = wg & (NCHUNK - 1);
  const int i = wg >> 3;
  const int t = threadIdx.x;
  const int r = t >> 5;         // row 0..15
  const int b = t & 31;         // 0..31

  __shared__ float blk[GRP * 400];   // 25.6 KB
  __shared__ int   xs[PCH * Bsz];    // [dp][b] -> bank = b, conflict-free
  __shared__ int   xi[Bsz];
  __shared__ float wred[32];

  // zero the k2 arrival ticket (ws re-poisoned each iteration; k1->k2 kernel
  // boundary publishes this store)
  if (wg == 0 && t == 0) *(int*)(ws + OFF_TICKET) = 0;

  const int pbase = c * PCH;
  for (int k = t; k < PCH * Bsz; k += BLK1) {
    int dp = k >> 5, bb = k & 31;
    xs[k] = x[bb * Lsz + pbase + dp];
  }
  if (t < Bsz) xi[t] = x[t * Lsz + i];

  float accJ0 = 0.f, accJ1 = 0.f, accE = 0.f, accC = 0.f, rsq = 0.f, rab = 0.f;

  // chunk = 12800 floats = 3200 float4; group = 1600 float4
  const float4* wrow = (const float4*)(wp + (size_t)(i * Lsz + pbase) * 400);
  float4 v0 = wrow[t];
  float4 v1 = wrow[t + 512];
  float4 v2 = wrow[t + 1024];
  float4 v3 = (t < 64) ? wrow[t + 1536] : make_float4(0.f, 0.f, 0.f, 0.f);

  const int jb0 = r * Asz;            // j = r
  const int jb1 = (16 + r) * Asz;     // j = 16 + r (rows 0..3 only)

  for (int g = 0; g < NGRP; ++g) {
    // stage current group: contiguous b128 writes, no index math
    float4* bf4 = (float4*)blk;
    bf4[t] = v0;
    bf4[t + 512] = v1;
    bf4[t + 1024] = v2;
    if (t < 64) bf4[t + 1536] = v3;   // wave-0-uniform
    rsq += v0.x*v0.x + v0.y*v0.y + v0.z*v0.z + v0.w*v0.w;
    rsq += v1.x*v1.x + v1.y*v1.y + v1.z*v1.z + v1.w*v1.w;
    rsq += v2.x*v2.x + v2.y*v2.y + v2.z*v2.z + v2.w*v2.w;
    rab += fabsf(v0.x)+fabsf(v0.y)+fabsf(v0.z)+fabsf(v0.w);
    rab += fabsf(v1.x)+fabsf(v1.y)+fabsf(v1.z)+fabsf(v1.w);
    rab += fabsf(v2.x)+fabsf(v2.y)+fabsf(v2.z)+fabsf(v2.w);
    if (t < 64) {
      rsq += v3.x*v3.x + v3.y*v3.y + v3.z*v3.z + v3.w*v3.w;
      rab += fabsf(v3.x)+fabsf(v3.y)+fabsf(v3.z)+fabsf(v3.w);
    }
    __syncthreads();

    // prefetch next group (register path overlaps barrier+gather)
    if (g == 0) {
      v0 = wrow[1600 + t];
      v1 = wrow[1600 + t + 512];
      v2 = wrow[1600 + t + 1024];
      if (t < 64) v3 = wrow[1600 + t + 1536];
    }

    const int p0 = pbase + g * GRP;   // global p of LDS block 0
    // --- accJ: p > i, uniform trip count; rows 0..3 handle a second j ---
    int ppstart = i + 1 - p0;
    if (ppstart < 0) ppstart = 0;
    if (t < 128) {                    // waves 0-1: two j's
      for (int pp = ppstart; pp < GRP; ++pp) {
        int xv = xs[((g * GRP + pp) << 5) | b];
        const float* row = blk + pp * 400 + xv;
        accJ0 += row[jb0];
        accJ1 += row[jb1];
      }
    } else {
      for (int pp = ppstart; pp < GRP; ++pp) {
        int xv = xs[((g * GRP + pp) << 5) | b];
        accJ0 += blk[pp * 400 + jb0 + xv];
      }
    }
    // --- accE (wave 7 lanes 0..31: t in [448,480)): all p ---
    if (t >= 448 && t < 448 + Bsz) {
      const int bb = t - 448;
      const int ebase = xi[bb] * Asz;
      for (int pp = 0; pp < GRP; ++pp) {
        int xv = xs[((g * GRP + pp) << 5) | bb];
        accE += blk[pp * 400 + ebase + xv];
      }
    } else if (t >= 480 && t < 480 + Asz) {
      // --- accC (wave 7 lanes 32..51): p<i -> col 19; p==i -> diag ---
      const int jj = t - 480;
      int pend = i - p0;
      if (pend > GRP) pend = GRP;
      for (int pp = 0; pp < pend; ++pp) accC += blk[pp * 400 + jj * Asz + 19];
      const int pd = i - p0;
      if (pd >= 0 && pd < GRP) accC += blk[pd * 400 + jj * Asz + jj];
    }
    __syncthreads();
  }

  // accJ stores: 512 + 128 values cover all (b, j in 0..19)
  {
    const size_t gb = OFF_G + (size_t)(c * Lsz + i) * Bsz * Asz;
    ws[gb + b * Asz + r] = accJ0;
    if (t < 128) ws[gb + b * Asz + 16 + r] = accJ1;
  }
  if (t >= 448 && t < 448 + Bsz) ws[OFF_E + (c * Lsz + i) * Bsz + (t - 448)] = accE;
  else if (t >= 480 && t < 480 + Asz) ws[OFF_C + (c * Lsz + i) * Asz + (t - 480)] = accC;

  // reg-stat reduction: wave shuffle then tiny LDS pass
  for (int s = 32; s >= 1; s >>= 1) {
    rsq += __shfl_down(rsq, s);
    rab += __shfl_down(rab, s);
  }
  if ((t & 63) == 0) { wred[t >> 6] = rsq; wred[16 + (t >> 6)] = rab; }
  __syncthreads();
  if (t == 0) {
    float a = 0.f, bb = 0.f;
    for (int w = 0; w < BLK1 / 64; ++w) { a += wred[w]; bb += wred[16 + w]; }
    ws[OFF_RSQ + wg] = a;
    ws[OFF_RAB + wg] = bb;
  }
}

// Kernel 2: one block per i (640 threads, t=j*32+b): assemble logits,
// logsumexp per (b), subtract energy, write per-(i,b) partial.
// The LAST block to finish (device-scope ticket, post-hot-path only) also
// performs the final scalar reduction (former k3).
__global__ __launch_bounds__(BLK2) void k2(const int* __restrict__ x,
                                           const float* __restrict__ wsng,
                                           float* __restrict__ ws,
                                           float* __restrict__ out) {
  const int i = blockIdx.x;
  const int t = threadIdx.x;
  const int j = t >> 5, b = t & 31;
  __shared__ float l[Bsz * 21];
  __shared__ float sred[16];
  __shared__ int lastFlag;

  float v = wsng[i * Asz + j];
  #pragma unroll
  for (int c = 0; c < NCHUNK; ++c) {
    v += ws[OFF_C + (c * Lsz + i) * Asz + j];
    v += ws[OFF_G + ((size_t)(c * Lsz + i) * Bsz + b) * Asz + j];
  }
  l[b * 21 + j] = v;
  __syncthreads();

  if (t < Bsz) {
    float m = -1e30f;
    #pragma unroll
    for (int jj = 0; jj < Asz; ++jj) m = fmaxf(m, l[t * 21 + jj]);
    float se = 0.f;
    #pragma unroll
    for (int jj = 0; jj < Asz; ++jj) se += __expf(l[t * 21 + jj] - m);
    float lse = m + __logf(se);
    float en = wsng[i * Asz + x[t * Lsz + i]];
    #pragma unroll
    for (int c = 0; c < NCHUNK; ++c) en += ws[OFF_E + (c * Lsz + i) * Bsz + t];
    ws[OFF_K2 + i * Bsz + t] = lse - en;
  }

  // ---- arrival ticket: last block does the final reduction ----
  __syncthreads();   // K2 row fully written by lanes t<32
  if (t == 0) {
    __threadfence(); // publish this block's K2 row (device scope)
    int old = __hip_atomic_fetch_add((int*)(ws + OFF_TICKET), 1,
                                     __ATOMIC_ACQ_REL, __HIP_MEMORY_SCOPE_AGENT);
    lastFlag = (old == Lsz - 1);
  }
  __syncthreads();
  if (!lastFlag) return;
  __threadfence();   // acquire: make all blocks' K2 rows visible

  // ---- former k3 body, strided over 640 threads ----
  float ssq = 0.f, sab = 0.f;
  for (int k = t; k < Lsz * Asz; k += BLK2) {
    float w = wsng[k];
    ssq += w * w; sab += fabsf(w);
  }
  float psq = 0.f, pab = 0.f;
  for (int k = t; k < NCHUNK * Lsz; k += BLK2) {
    psq += ws[OFF_RSQ + k];
    pab += ws[OFF_RAB + k];
  }
  float fe = 0.f;
  for (int k = t; k < Lsz * Bsz; k += BLK2) fe += ws[OFF_K2 + k];

  const float LP = 51.0f;  // 0.2 * (L-1)
  float val = fe * (1.0f / Bsz) + (ssq + sab) + LP * (psq + pab);

  for (int s = 32; s >= 1; s >>= 1) val += __shfl_down(val, s);
  if ((t & 63) == 0) sred[t >> 6] = val;
  __syncthreads();
  if (t == 0) {
    float a = 0.f;
    for (int w = 0; w < BLK2 / 64; ++w) a += sred[w];
    out[0] = a;
  }
}

extern "C" void kernel_launch(void* const* d_in, const int* in_sizes, int n_in,
                              void* d_out, int out_size, void* d_ws, size_t ws_size,
                              hipStream_t stream) {
  const int*   x       = (const int*)d_in[0];
  const float* wsingle = (const float*)d_in[1];
  const float* wpair   = (const float*)d_in[2];
  float* ws  = (float*)d_ws;
  float* out = (float*)d_out;

  k1<<<Lsz * NCHUNK, BLK1, 0, stream>>>(x, wpair, ws);
  k2<<<Lsz, BLK2, 0, stream>>>(x, wsingle, ws, out);
}

// Round 7
// 178.950 us; speedup vs baseline: 4.7281x; 1.0010x over previous
//
#include <hip/hip_runtime.h>
#include <cmath>

// Problem constants
#define Bsz 32
#define Lsz 256
#define Asz 20
#define NCHUNK 8        // p-chunks per i (32 p each)
#define PCH 32          // L / NCHUNK
#define GRP 16          // blocks staged per LDS group (16*400 = 6400 floats)
#define NGRP 2          // groups per chunk
#define BLK1 640        // t = j*32 + b  (j=t>>5 in 0..19, b=t&31)

// Workspace offsets (floats). Total ~1.43M floats = 5.7 MB.
#define OFF_G 0                                    // [c][i][b][j] p>i gather partials
#define OFF_C (NCHUNK*Lsz*Bsz*Asz)                 // [c][i][j]    b-independent (p<=i)
#define OFF_E (OFF_C + NCHUNK*Lsz*Asz)             // [c][i][b]    energy pair partials
#define OFF_RSQ (OFF_E + NCHUNK*Lsz*Bsz)           // [2048] per-wg sum w^2
#define OFF_RAB (OFF_RSQ + NCHUNK*Lsz)             // [2048] per-wg sum |w|
#define OFF_K2  (OFF_RAB + NCHUNK*Lsz)             // [L*B]  per-(i,b) lse-energy
#define OFF_TICKET (OFF_K2 + Lsz*Bsz)              // [1]    k2 arrival counter (int)

// Kernel 1: stream all of w_pair once. wg = (i, chunk c), grid 2048.
// Raw (unpadded) LDS block layout; lane map t=j*32+b makes the gather
// conflict-free (<=40 consecutive words per wave -> 2-way max, free).
__global__ __launch_bounds__(BLK1, 8) void k1(const int* __restrict__ x,
                                              const float* __restrict__ wp,
                                              float* __restrict__ ws) {
  const int wg = blockIdx.x;
  const int c = wg & (NCHUNK - 1);
  const int i = wg >> 3;
  const int t = threadIdx.x;
  const int j = t >> 5;         // 0..19
  const int b = t & 31;         // 0..31

  __shared__ float blk[GRP * 400];   // 25.6 KB
  __shared__ int   xs[PCH * Bsz];    // [dp][b] -> bank = b, conflict-free
  __shared__ int   xi[Bsz];
  __shared__ float wred[32];

  // zero the k2 arrival ticket (ws is re-poisoned before k1 each iteration;
  // k1->k2 kernel boundary publishes this store)
  if (wg == 0 && t == 0) *(int*)(ws + OFF_TICKET) = 0;

  const int pbase = c * PCH;
  for (int k = t; k < PCH * Bsz; k += BLK1) {
    int dp = k >> 5, bb = k & 31;
    xs[k] = x[bb * Lsz + pbase + dp];
  }
  if (t < Bsz) xi[t] = x[t * Lsz + i];

  float accJ = 0.f, accE = 0.f, accC = 0.f, rsq = 0.f, rab = 0.f;

  // chunk = 12800 floats = 3200 float4; group = 1600 float4
  const float4* wrow = (const float4*)(wp + (size_t)(i * Lsz + pbase) * 400);
  float4 v0 = wrow[t];
  float4 v1 = wrow[t + 640];
  float4 v2 = (t < 320) ? wrow[t + 1280] : make_float4(0.f, 0.f, 0.f, 0.f);

  for (int g = 0; g < NGRP; ++g) {
    // stage current group: contiguous b128 writes, no index math
    float4* bf4 = (float4*)blk;
    bf4[t] = v0;
    bf4[t + 640] = v1;
    if (t < 320) bf4[t + 1280] = v2;
    rsq += v0.x*v0.x + v0.y*v0.y + v0.z*v0.z + v0.w*v0.w;
    rsq += v1.x*v1.x + v1.y*v1.y + v1.z*v1.z + v1.w*v1.w;
    rab += fabsf(v0.x)+fabsf(v0.y)+fabsf(v0.z)+fabsf(v0.w);
    rab += fabsf(v1.x)+fabsf(v1.y)+fabsf(v1.z)+fabsf(v1.w);
    if (t < 320) {
      rsq += v2.x*v2.x + v2.y*v2.y + v2.z*v2.z + v2.w*v2.w;
      rab += fabsf(v2.x)+fabsf(v2.y)+fabsf(v2.z)+fabsf(v2.w);
    }
    __syncthreads();

    // prefetch next group (register path overlaps barrier+gather)
    if (g == 0) {
      v0 = wrow[1600 + t];
      v1 = wrow[1600 + t + 640];
      if (t < 320) v2 = wrow[1600 + t + 1280];
    }

    const int p0 = pbase + g * GRP;   // global p of LDS block 0
    // --- accJ: p > i, all waves, uniform trip count ---
    int ppstart = i + 1 - p0;
    if (ppstart < 0) ppstart = 0;
    const int jbase = j * Asz;
    for (int pp = ppstart; pp < GRP; ++pp) {
      int xv = xs[((g * GRP + pp) << 5) | b];
      accJ += blk[pp * 400 + jbase + xv];
    }
    // --- accE (lanes 0..31 of wave 0): all p ---
    if (t < Bsz) {
      const int ebase = xi[t] * Asz;
      for (int pp = 0; pp < GRP; ++pp) {
        int xv = xs[((g * GRP + pp) << 5) | t];
        accE += blk[pp * 400 + ebase + xv];
      }
    } else if (t < Bsz + Asz) {
      // --- accC (lanes 32..51 of wave 0): p<i -> col 19; p==i -> diag ---
      const int jj = t - Bsz;
      int pend = i - p0;
      if (pend > GRP) pend = GRP;
      for (int pp = 0; pp < pend; ++pp) accC += blk[pp * 400 + jj * Asz + 19];
      const int pd = i - p0;
      if (pd >= 0 && pd < GRP) accC += blk[pd * 400 + jj * Asz + jj];
    }
    __syncthreads();
  }

  ws[OFF_G + ((size_t)(c * Lsz + i) * Bsz + b) * Asz + j] = accJ;
  if (t < Bsz) ws[OFF_E + (c * Lsz + i) * Bsz + t] = accE;
  else if (t < Bsz + Asz) ws[OFF_C + (c * Lsz + i) * Asz + (t - Bsz)] = accC;

  // reg-stat reduction: wave shuffle then tiny LDS pass
  for (int s = 32; s >= 1; s >>= 1) {
    rsq += __shfl_down(rsq, s);
    rab += __shfl_down(rab, s);
  }
  if ((t & 63) == 0) { wred[t >> 6] = rsq; wred[16 + (t >> 6)] = rab; }
  __syncthreads();
  if (t == 0) {
    float a = 0.f, bb = 0.f;
    for (int w = 0; w < 10; ++w) { a += wred[w]; bb += wred[16 + w]; }
    ws[OFF_RSQ + wg] = a;
    ws[OFF_RAB + wg] = bb;
  }
}

// Kernel 2: one block per i (640 threads, t=j*32+b): assemble logits,
// logsumexp per (b), subtract energy, write per-(i,b) partial.
// The LAST block to finish (device-scope ticket) also performs the final
// scalar reduction (former k3), saving one kernel launch.
__global__ __launch_bounds__(BLK1) void k2(const int* __restrict__ x,
                                           const float* __restrict__ wsng,
                                           float* __restrict__ ws,
                                           float* __restrict__ out) {
  const int i = blockIdx.x;
  const int t = threadIdx.x;
  const int j = t >> 5, b = t & 31;
  __shared__ float l[Bsz * 21];
  __shared__ float sred[16];
  __shared__ int lastFlag;

  float v = wsng[i * Asz + j];
  #pragma unroll
  for (int c = 0; c < NCHUNK; ++c) {
    v += ws[OFF_C + (c * Lsz + i) * Asz + j];
    v += ws[OFF_G + ((size_t)(c * Lsz + i) * Bsz + b) * Asz + j];
  }
  l[b * 21 + j] = v;
  __syncthreads();

  if (t < Bsz) {
    float m = -1e30f;
    #pragma unroll
    for (int jj = 0; jj < Asz; ++jj) m = fmaxf(m, l[t * 21 + jj]);
    float se = 0.f;
    #pragma unroll
    for (int jj = 0; jj < Asz; ++jj) se += __expf(l[t * 21 + jj] - m);
    float lse = m + __logf(se);
    float en = wsng[i * Asz + x[t * Lsz + i]];
    #pragma unroll
    for (int c = 0; c < NCHUNK; ++c) en += ws[OFF_E + (c * Lsz + i) * Bsz + t];
    ws[OFF_K2 + i * Bsz + t] = lse - en;
  }

  // ---- arrival ticket: last block does the final reduction ----
  __syncthreads();   // K2 row fully written by lanes t<32
  if (t == 0) {
    __threadfence(); // publish this block's K2 row (device scope)
    int old = __hip_atomic_fetch_add((int*)(ws + OFF_TICKET), 1,
                                     __ATOMIC_ACQ_REL, __HIP_MEMORY_SCOPE_AGENT);
    lastFlag = (old == Lsz - 1);
  }
  __syncthreads();
  if (!lastFlag) return;
  __threadfence();   // acquire: make all blocks' K2 rows visible

  // ---- former k3 body, strided over 640 threads ----
  float ssq = 0.f, sab = 0.f;
  for (int k = t; k < Lsz * Asz; k += BLK1) {
    float w = wsng[k];
    ssq += w * w; sab += fabsf(w);
  }
  float psq = 0.f, pab = 0.f;
  for (int k = t; k < NCHUNK * Lsz; k += BLK1) {
    psq += ws[OFF_RSQ + k];
    pab += ws[OFF_RAB + k];
  }
  float fe = 0.f;
  for (int k = t; k < Lsz * Bsz; k += BLK1) fe += ws[OFF_K2 + k];

  const float LP = 51.0f;  // 0.2 * (L-1)
  float val = fe * (1.0f / Bsz) + (ssq + sab) + LP * (psq + pab);

  for (int s = 32; s >= 1; s >>= 1) val += __shfl_down(val, s);
  if ((t & 63) == 0) sred[t >> 6] = val;
  __syncthreads();
  if (t == 0) {
    float a = 0.f;
    for (int w = 0; w < BLK1 / 64; ++w) a += sred[w];
    out[0] = a;
  }
}

extern "C" void kernel_launch(void* const* d_in, const int* in_sizes, int n_in,
                              void* d_out, int out_size, void* d_ws, size_t ws_size,
                              hipStream_t stream) {
  const int*   x       = (const int*)d_in[0];
  const float* wsingle = (const float*)d_in[1];
  const float* wpair   = (const float*)d_in[2];
  float* ws  = (float*)d_ws;
  float* out = (float*)d_out;

  k1<<<Lsz * NCHUNK, BLK1, 0, stream>>>(x, wpair, ws);
  k2<<<Lsz, BLK1, 0, stream>>>(x, wsingle, ws, out);
}